// Round 1
// baseline (2884.795 us; speedup 1.0000x reference)
//
#include <hip/hip_runtime.h>

// ---------------- problem constants ----------------
#define V_CODES 8192
#define D_DIM   256
#define SPATIAL 4096            // 16*16*16
#define M_ROWS  32768           // 8 * 4096
#define NELEM   8388608         // M_ROWS * D_DIM

static constexpr float GAMMA_F = 0.99f;
static constexpr float OMG_F   = (float)(1.0 - 0.99);     // matches jnp (1.0 - GAMMA) folded to f32
static constexpr float EPS_F   = 1e-7f;
static constexpr float VEPS_F  = (float)(8192 * 1e-7);    // V * EPS

// output layout (floats), concatenated in reference return order
static constexpr size_t OFF_QUANT = 0;            // 8388608  quant_st
static constexpr size_t OFF_IDX   = 8388608;      // 32768    enc_idx (stored as float)
static constexpr size_t OFF_QDIFF = 8421376;      // 1        quant_diff
static constexpr size_t OFF_NN    = 8421377;      // 8192     new_N
static constexpr size_t OFF_ZAVG  = 8429569;      // 2097152  new_z_avg
static constexpr size_t OFF_W     = 10526721;     // 2097152  new_weight

// ---------------- K0a: weight row norms + init new_N = gamma*N ----------------
__global__ void k_wnorm(const float* __restrict__ W, const float* __restrict__ N,
                        float* __restrict__ wnorm, float* __restrict__ outNN) {
    int v = blockIdx.x * 4 + (threadIdx.x >> 6);
    int lane = threadIdx.x & 63;
    float4 w4 = *(const float4*)(W + (size_t)v * D_DIM + lane * 4);
    float s = w4.x * w4.x + w4.y * w4.y + w4.z * w4.z + w4.w * w4.w;
    #pragma unroll
    for (int m = 32; m > 0; m >>= 1) s += __shfl_xor(s, m, 64);
    if (lane == 0) {
        wnorm[v] = s;
        outNN[v] = GAMMA_F * N[v];
    }
}

// ---------------- K0b: init new_z_avg = gamma * z_avg ----------------
__global__ void k_scale_zavg(const float* __restrict__ zavg, float* __restrict__ out) {
    int i = blockIdx.x * 256 + threadIdx.x;
    out[i] = GAMMA_F * zavg[i];
}

// ---------------- K1: fused distance GEMM + argmin ----------------
// score(m,v) = ||w_v||^2 - 2 * z_m . w_v   (||z||^2 dropped: row-constant)
#define MT 64
#define VT 128
#define KT 32
#define APAD 68    // 64 + 4
#define BPAD 132   // 128 + 4

__global__ __launch_bounds__(256, 2) void k_argmin(
        const float* __restrict__ X, const float* __restrict__ W,
        const float* __restrict__ wnorm, int* __restrict__ idx_out) {
    __shared__ float Alds[KT * APAD];
    __shared__ float Blds[KT * BPAD];
    const int tid = threadIdx.x;
    const int m0  = blockIdx.x * MT;
    const int b   = m0 >> 12;          // 4096 rows per batch image
    const int sp0 = m0 & 4095;
    const float* xbase = X + (size_t)b * D_DIM * SPATIAL + sp0;  // element (k,m): xbase[k*4096 + m]

    const int trow = tid >> 4;   // 0..15 -> 4 m-rows each
    const int tcol = tid & 15;   // 0..15 -> 8 v-cols each

    float best[4];
    int   bidx[4];
    #pragma unroll
    for (int i = 0; i < 4; i++) { best[i] = 3.4e38f; bidx[i] = 0; }

    const int akk = tid >> 3;           // A stage: k row 0..31
    const int aj  = tid & 7;            // A stage: float4 col base
    const int bvv = tid & 127;          // B stage: v row
    const int bjj = (tid >> 7) * 4;     // B stage: first float4 index (0 or 4)

    for (int v0 = 0; v0 < V_CODES; v0 += VT) {
        float acc[4][8];
        #pragma unroll
        for (int i = 0; i < 4; i++)
            #pragma unroll
            for (int j = 0; j < 8; j++) acc[i][j] = 0.0f;

        for (int k0 = 0; k0 < D_DIM; k0 += KT) {
            __syncthreads();
            // stage A tile: LDS[k][m], m contiguous (coalesced along spatial)
            {
                const float* src = xbase + (size_t)(k0 + akk) * SPATIAL + aj * 4;
                float4 a0 = *(const float4*)(src);
                float4 a1 = *(const float4*)(src + 32);
                *(float4*)&Alds[akk * APAD + aj * 4]      = a0;
                *(float4*)&Alds[akk * APAD + aj * 4 + 32] = a1;
            }
            // stage B tile: transpose [v][k] -> LDS[k][v]
            {
                const float* src = W + (size_t)(v0 + bvv) * D_DIM + k0 + bjj * 4;
                float4 q[4];
                #pragma unroll
                for (int f = 0; f < 4; f++) q[f] = *(const float4*)(src + f * 4);
                #pragma unroll
                for (int f = 0; f < 4; f++) {
                    int kl = (bjj + f) * 4;
                    Blds[(kl + 0) * BPAD + bvv] = q[f].x;
                    Blds[(kl + 1) * BPAD + bvv] = q[f].y;
                    Blds[(kl + 2) * BPAD + bvv] = q[f].z;
                    Blds[(kl + 3) * BPAD + bvv] = q[f].w;
                }
            }
            __syncthreads();
            // compute 4x8 register tile over 32 k's
            #pragma unroll
            for (int kk = 0; kk < KT; kk++) {
                float4 a4 = *(const float4*)&Alds[kk * APAD + trow * 4];
                float4 b0 = *(const float4*)&Blds[kk * BPAD + tcol * 8];
                float4 b1 = *(const float4*)&Blds[kk * BPAD + tcol * 8 + 4];
                float av[4] = {a4.x, a4.y, a4.z, a4.w};
                float bv[8] = {b0.x, b0.y, b0.z, b0.w, b1.x, b1.y, b1.z, b1.w};
                #pragma unroll
                for (int i = 0; i < 4; i++)
                    #pragma unroll
                    for (int j = 0; j < 8; j++)
                        acc[i][j] = fmaf(av[i], bv[j], acc[i][j]);
            }
        }
        // fold into running argmin (v ascending -> first-index tie-break)
        #pragma unroll
        for (int j = 0; j < 8; j++) {
            int v = v0 + tcol * 8 + j;
            float wn = wnorm[v];
            #pragma unroll
            for (int i = 0; i < 4; i++) {
                float s = wn - 2.0f * acc[i][j];
                if (s < best[i]) { best[i] = s; bidx[i] = v; }
            }
        }
    }
    // reduce across the 16 v-column threads (lane bits 0..3)
    #pragma unroll
    for (int msk = 1; msk < 16; msk <<= 1) {
        #pragma unroll
        for (int i = 0; i < 4; i++) {
            float ob = __shfl_xor(best[i], msk, 64);
            int   oi = __shfl_xor(bidx[i], msk, 64);
            if (ob < best[i] || (ob == best[i] && oi < bidx[i])) { best[i] = ob; bidx[i] = oi; }
        }
    }
    if (tcol == 0) {
        #pragma unroll
        for (int i = 0; i < 4; i++) idx_out[m0 + trow * 4 + i] = bidx[i];
    }
}

// ---------------- K2: gather quant, write outputs, scatter EMA stats ----------------
__global__ void k_scatter(const float* __restrict__ X, const float* __restrict__ W,
                          const int* __restrict__ idx, float* __restrict__ out,
                          float* __restrict__ ws_scal) {
    int e  = blockIdx.x * 256 + threadIdx.x;   // element in (b, d, sp) order
    int sp = e & 4095;
    int bd = e >> 12;
    int d  = bd & 255;
    int b  = bd >> 8;
    int m  = b * SPATIAL + sp;
    int v  = idx[m];
    float xv = X[e];
    float wv = W[(size_t)v * D_DIM + d];
    out[OFF_QUANT + e] = (wv - xv) + xv;       // straight-through: (quant - x) + x
    float df = xv - wv;
    float p  = df * df;
    atomicAdd(out + OFF_ZAVG + (size_t)v * D_DIM + d, OMG_F * xv);
    if (d == 0) {
        atomicAdd(out + OFF_NN + v, OMG_F);
        out[OFF_IDX + m] = (float)v;
    }
    __shared__ float red[256];
    red[threadIdx.x] = p;
    __syncthreads();
    #pragma unroll
    for (int s = 128; s > 0; s >>= 1) {
        if (threadIdx.x < s) red[threadIdx.x] += red[threadIdx.x + s];
        __syncthreads();
    }
    if (threadIdx.x == 0) atomicAdd(ws_scal, red[0]);
}

// ---------------- K3a: n = sum(new_N); finalize quant_diff ----------------
__global__ void k_finalize_n(const float* __restrict__ outNN, float* __restrict__ ws_scal,
                             float* __restrict__ out_qdiff) {
    __shared__ float red[256];
    float s = 0.0f;
    for (int v = threadIdx.x; v < V_CODES; v += 256) s += outNN[v];
    red[threadIdx.x] = s;
    __syncthreads();
    #pragma unroll
    for (int t = 128; t > 0; t >>= 1) {
        if (threadIdx.x < t) red[threadIdx.x] += red[threadIdx.x + t];
        __syncthreads();
    }
    if (threadIdx.x == 0) {
        ws_scal[1] = red[0];
        out_qdiff[0] = ws_scal[0] * (1.0f / 8388608.0f);
    }
}

// ---------------- K3b: new_weight = new_z_avg / w ----------------
__global__ void k_weight(const float* __restrict__ zavg_out, const float* __restrict__ nn_out,
                         const float* __restrict__ ws_scal, float* __restrict__ out_w) {
    int i = blockIdx.x * 256 + threadIdx.x;
    int v = i >> 8;
    float n = ws_scal[1];
    float w = (nn_out[v] + EPS_F) / (n + VEPS_F) * n;
    out_w[i] = zavg_out[i] / w;
}

extern "C" void kernel_launch(void* const* d_in, const int* in_sizes, int n_in,
                              void* d_out, int out_size, void* d_ws, size_t ws_size,
                              hipStream_t stream) {
    const float* x    = (const float*)d_in[0];
    const float* w    = (const float*)d_in[1];
    const float* N    = (const float*)d_in[2];
    const float* zavg = (const float*)d_in[3];
    float* out = (float*)d_out;
    float* ws  = (float*)d_ws;

    float* ws_scal  = ws;                       // [0]=qdiff sum, [1]=n
    float* ws_wnorm = ws + 16;                  // 8192 floats
    int*   ws_idx   = (int*)(ws + 16 + V_CODES); // 32768 ints  (~160 KB total ws use)

    hipMemsetAsync(ws, 0, 8, stream);
    k_wnorm     <<<V_CODES / 4, 256, 0, stream>>>(w, N, ws_wnorm, out + OFF_NN);
    k_scale_zavg<<<(V_CODES * D_DIM) / 256, 256, 0, stream>>>(zavg, out + OFF_ZAVG);
    k_argmin    <<<M_ROWS / MT, 256, 0, stream>>>(x, w, ws_wnorm, ws_idx);
    k_scatter   <<<NELEM / 256, 256, 0, stream>>>(x, w, ws_idx, out, ws_scal);
    k_finalize_n<<<1, 256, 0, stream>>>(out + OFF_NN, ws_scal, out + OFF_QDIFF);
    k_weight    <<<(V_CODES * D_DIM) / 256, 256, 0, stream>>>(out + OFF_ZAVG, out + OFF_NN, ws_scal, out + OFF_W);
}

// Round 2
// 1484.203 us; speedup vs baseline: 1.9437x; 1.9437x over previous
//
#include <hip/hip_runtime.h>

// ---------------- problem constants ----------------
#define V_CODES 8192
#define D_DIM   256
#define SPATIAL 4096            // 16*16*16
#define M_ROWS  32768           // 8 * 4096
#define NELEM   8388608         // M_ROWS * D_DIM

static constexpr float GAMMA_F = 0.99f;
static constexpr float OMG_F   = (float)(1.0 - 0.99);
static constexpr float EPS_F   = 1e-7f;
static constexpr float VEPS_F  = (float)(8192 * 1e-7);

// output layout (floats), concatenated in reference return order
static constexpr size_t OFF_QUANT = 0;            // 8388608  quant_st
static constexpr size_t OFF_IDX   = 8388608;      // 32768    enc_idx (stored as float)
static constexpr size_t OFF_QDIFF = 8421376;      // 1        quant_diff
static constexpr size_t OFF_NN    = 8421377;      // 8192     new_N
static constexpr size_t OFF_ZAVG  = 8429569;      // 2097152  new_z_avg
static constexpr size_t OFF_W     = 10526721;     // 2097152  new_weight

typedef _Float16 f16x8 __attribute__((ext_vector_type(8)));
typedef float    f32x4 __attribute__((ext_vector_type(4)));

// async global->LDS, 16B per lane; LDS dest is wave-uniform base + lane*16
#define GLL(gp, lp) __builtin_amdgcn_global_load_lds( \
    (const __attribute__((address_space(1))) unsigned int*)(gp), \
    (__attribute__((address_space(3))) unsigned int*)(lp), 16, 0, 0)

// ---------------- K0a: weight row norms (fp32) + init new_N = gamma*N ----------------
__global__ void k_wnorm(const float* __restrict__ W, const float* __restrict__ N,
                        float* __restrict__ wnorm, float* __restrict__ outNN) {
    int v = blockIdx.x * 4 + (threadIdx.x >> 6);
    int lane = threadIdx.x & 63;
    float4 w4 = *(const float4*)(W + (size_t)v * D_DIM + lane * 4);
    float s = w4.x * w4.x + w4.y * w4.y + w4.z * w4.z + w4.w * w4.w;
    #pragma unroll
    for (int m = 32; m > 0; m >>= 1) s += __shfl_xor(s, m, 64);
    if (lane == 0) {
        wnorm[v] = s;
        outNN[v] = GAMMA_F * N[v];
    }
}

// ---------------- K0b: init new_z_avg = gamma * z_avg ----------------
__global__ void k_scale_zavg(const float* __restrict__ zavg, float* __restrict__ out) {
    int i = blockIdx.x * 256 + threadIdx.x;
    out[i] = GAMMA_F * zavg[i];
}

// ---------------- K0c: split W (V x 256, k-contiguous) into fp16 hi/lo planes ----------------
__global__ void k_split_w(const float* __restrict__ W, _Float16* __restrict__ Wh,
                          _Float16* __restrict__ Wl) {
    size_t i8 = ((size_t)blockIdx.x * 256 + threadIdx.x) * 8;
    float4 a = *(const float4*)(W + i8);
    float4 b = *(const float4*)(W + i8 + 4);
    float v[8] = {a.x, a.y, a.z, a.w, b.x, b.y, b.z, b.w};
    f16x8 hi, lo;
    #pragma unroll
    for (int j = 0; j < 8; j++) {
        _Float16 h = (_Float16)v[j];
        hi[j] = h;
        lo[j] = (_Float16)(v[j] - (float)h);
    }
    *(f16x8*)(Wh + i8) = hi;
    *(f16x8*)(Wl + i8) = lo;
}

// ---------------- K0d: split + transpose X (b,k,sp) -> Xh/Xl (m, k) row-major ----------------
// block: 256 threads; lane = m within 64-row tile; (tid>>6) selects k-group of 32
__global__ void k_split_x(const float* __restrict__ X, _Float16* __restrict__ Xh,
                          _Float16* __restrict__ Xl) {
    int bid  = blockIdx.x;            // 1024 blocks
    int lane = threadIdx.x & 63;
    int kg   = (bid & 1) * 4 + (threadIdx.x >> 6);   // 0..7 -> k base kg*32
    int m    = (bid >> 1) * 64 + lane;
    int b  = m >> 12;
    int sp = m & 4095;
    const float* src = X + (size_t)b * (D_DIM * SPATIAL) + (size_t)(kg * 32) * SPATIAL + sp;
    float v[32];
    #pragma unroll
    for (int j = 0; j < 32; j++) v[j] = src[(size_t)j * SPATIAL];   // coalesced across lanes
    _Float16* dh = Xh + (size_t)m * D_DIM + kg * 32;
    _Float16* dl = Xl + (size_t)m * D_DIM + kg * 32;
    #pragma unroll
    for (int c = 0; c < 4; c++) {
        f16x8 hi, lo;
        #pragma unroll
        for (int j = 0; j < 8; j++) {
            float x = v[c * 8 + j];
            _Float16 h = (_Float16)x;
            hi[j] = h;
            lo[j] = (_Float16)(x - (float)h);
        }
        *(f16x8*)(dh + c * 8) = hi;
        *(f16x8*)(dl + c * 8) = lo;
    }
}

// ---------------- K1: MFMA distance GEMM + argmin (v-split, atomicMin merge) ----------------
// score(m,v) = ||w_v||^2 - 2 * dot(x_m, w_v); dot via fp16 hi/lo 3-product split.
// Block tile 128m x 128v, 4 waves as 2x2 of 64x64. K-step 32, 16x16x32_f16 MFMA.
__device__ inline unsigned long long packkey(float s, int v) {
    unsigned u = __float_as_uint(s);
    u = (u & 0x80000000u) ? ~u : (u | 0x80000000u);
    return ((unsigned long long)u << 32) | (unsigned)v;
}

__global__ __launch_bounds__(256, 2) void k_mfma_argmin(
        const _Float16* __restrict__ Xh, const _Float16* __restrict__ Xl,
        const _Float16* __restrict__ Wh, const _Float16* __restrict__ Wl,
        const float* __restrict__ wnorm, unsigned long long* __restrict__ best) {
    // LDS in fragment order: region r (1 KB = 512 f16) = one 16-row x 32-k subtile,
    // lane l holds 8 contiguous k for row (l&15), k-chunk (l>>4). regions:
    // 0-7: Ah subs, 8-15: Al, 16-23: Bh, 24-31: Bl
    __shared__ __align__(16) _Float16 lds[16384];
    const int tid  = threadIdx.x;
    const int wid  = tid >> 6;
    const int lane = tid & 63;
    const int wy = wid >> 1, wx = wid & 1;
    const int lrow = lane & 15, lq = lane >> 4;
    const int m0 = blockIdx.y * 128;
    const int v0 = blockIdx.x * 128;

    f32x4 acc[4][4] = {};

    const _Float16* planes[4] = {Xh, Xl, Wh, Wl};
    // this wave stages regions wid*8 .. wid*8+7 (one full plane)
    const _Float16* P = planes[wid];
    const int rowb = (wid < 2 ? m0 : v0) + lrow;

    for (int k0 = 0; k0 < D_DIM; k0 += 32) {
        __syncthreads();
        #pragma unroll
        for (int sub = 0; sub < 8; sub++) {
            const _Float16* g = P + (size_t)(rowb + sub * 16) * D_DIM + k0 + lq * 8;
            GLL(g, &lds[(wid * 8 + sub) * 512]);
        }
        __syncthreads();
        f16x8 ah[4], al[4], bh[4], bl[4];
        #pragma unroll
        for (int i = 0; i < 4; i++) {
            ah[i] = *(const f16x8*)&lds[(      wy * 4 + i) * 512 + lane * 8];
            al[i] = *(const f16x8*)&lds[( 8 + wy * 4 + i) * 512 + lane * 8];
            bh[i] = *(const f16x8*)&lds[(16 + wx * 4 + i) * 512 + lane * 8];
            bl[i] = *(const f16x8*)&lds[(24 + wx * 4 + i) * 512 + lane * 8];
        }
        #pragma unroll
        for (int mi = 0; mi < 4; mi++)
            #pragma unroll
            for (int vi = 0; vi < 4; vi++) {
                acc[mi][vi] = __builtin_amdgcn_mfma_f32_16x16x32_f16(ah[mi], bh[vi], acc[mi][vi], 0, 0, 0);
                acc[mi][vi] = __builtin_amdgcn_mfma_f32_16x16x32_f16(al[mi], bh[vi], acc[mi][vi], 0, 0, 0);
                acc[mi][vi] = __builtin_amdgcn_mfma_f32_16x16x32_f16(ah[mi], bl[vi], acc[mi][vi], 0, 0, 0);
            }
    }

    // epilogue: C layout col=lane&15 (v), row=(lane>>4)*4+reg (m)
    float wnv[4];
    #pragma unroll
    for (int vi = 0; vi < 4; vi++) wnv[vi] = wnorm[v0 + (wx * 4 + vi) * 16 + lrow];

    #pragma unroll
    for (int mi = 0; mi < 4; mi++) {
        #pragma unroll
        for (int r = 0; r < 4; r++) {
            unsigned long long k = ~0ull;
            #pragma unroll
            for (int vi = 0; vi < 4; vi++) {
                int v = v0 + (wx * 4 + vi) * 16 + lrow;
                float s = wnv[vi] - 2.0f * acc[mi][vi][r];
                unsigned long long key = packkey(s, v);
                k = key < k ? key : k;
            }
            #pragma unroll
            for (int msk = 1; msk < 16; msk <<= 1) {
                unsigned long long o = __shfl_xor(k, msk, 64);
                k = o < k ? o : k;
            }
            if (lrow == 0) {
                int m = m0 + (wy * 4 + mi) * 16 + lq * 4 + r;
                atomicMin(&best[m], k);
            }
        }
    }
}

// ---------------- K2: gather quant, write outputs, scatter EMA stats ----------------
__global__ void k_scatter(const float* __restrict__ X, const float* __restrict__ W,
                          const unsigned long long* __restrict__ best, float* __restrict__ out,
                          float* __restrict__ ws_scal) {
    int e  = blockIdx.x * 256 + threadIdx.x;   // element in (b, d, sp) order
    int sp = e & 4095;
    int bd = e >> 12;
    int d  = bd & 255;
    int b  = bd >> 8;
    int m  = b * SPATIAL + sp;
    int v  = (int)(unsigned)(best[m] & 0xFFFFFFFFull);
    float xv = X[e];
    float wv = W[(size_t)v * D_DIM + d];
    out[OFF_QUANT + e] = (wv - xv) + xv;       // straight-through
    float df = xv - wv;
    float p  = df * df;
    atomicAdd(out + OFF_ZAVG + (size_t)v * D_DIM + d, OMG_F * xv);
    if (d == 0) {
        atomicAdd(out + OFF_NN + v, OMG_F);
        out[OFF_IDX + m] = (float)v;
    }
    __shared__ float red[256];
    red[threadIdx.x] = p;
    __syncthreads();
    #pragma unroll
    for (int s = 128; s > 0; s >>= 1) {
        if (threadIdx.x < s) red[threadIdx.x] += red[threadIdx.x + s];
        __syncthreads();
    }
    if (threadIdx.x == 0) atomicAdd(ws_scal, red[0]);
}

// ---------------- K3a: n = sum(new_N); finalize quant_diff ----------------
__global__ void k_finalize_n(const float* __restrict__ outNN, float* __restrict__ ws_scal,
                             float* __restrict__ out_qdiff) {
    __shared__ float red[256];
    float s = 0.0f;
    for (int v = threadIdx.x; v < V_CODES; v += 256) s += outNN[v];
    red[threadIdx.x] = s;
    __syncthreads();
    #pragma unroll
    for (int t = 128; t > 0; t >>= 1) {
        if (threadIdx.x < t) red[threadIdx.x] += red[threadIdx.x + t];
        __syncthreads();
    }
    if (threadIdx.x == 0) {
        ws_scal[1] = red[0];
        out_qdiff[0] = ws_scal[0] * (1.0f / 8388608.0f);
    }
}

// ---------------- K3b: new_weight = new_z_avg / w ----------------
__global__ void k_weight(const float* __restrict__ zavg_out, const float* __restrict__ nn_out,
                         const float* __restrict__ ws_scal, float* __restrict__ out_w) {
    int i = blockIdx.x * 256 + threadIdx.x;
    int v = i >> 8;
    float n = ws_scal[1];
    float w = (nn_out[v] + EPS_F) / (n + VEPS_F) * n;
    out_w[i] = zavg_out[i] / w;
}

extern "C" void kernel_launch(void* const* d_in, const int* in_sizes, int n_in,
                              void* d_out, int out_size, void* d_ws, size_t ws_size,
                              hipStream_t stream) {
    const float* x    = (const float*)d_in[0];
    const float* w    = (const float*)d_in[1];
    const float* N    = (const float*)d_in[2];
    const float* zavg = (const float*)d_in[3];
    float* out = (float*)d_out;
    char*  wsb = (char*)d_ws;

    // workspace layout (bytes)
    float* ws_scal  = (float*)wsb;                                   // 64 B
    float* ws_wnorm = (float*)(wsb + 64);                            // 32 KB
    unsigned long long* ws_best = (unsigned long long*)(wsb + 32832); // 256 KB
    _Float16* Xh = (_Float16*)(wsb + 294976);                        // 16.78 MB
    _Float16* Xl = (_Float16*)(wsb + 294976 + 16777216);
    _Float16* Wh = (_Float16*)(wsb + 294976 + 2 * 16777216);         // 4.19 MB
    _Float16* Wl = (_Float16*)(wsb + 294976 + 2 * 16777216 + 4194304);
    // total ~42.3 MB

    hipMemsetAsync(ws_scal, 0, 8, stream);
    hipMemsetAsync(ws_best, 0xFF, (size_t)M_ROWS * 8, stream);

    k_wnorm     <<<V_CODES / 4, 256, 0, stream>>>(w, N, ws_wnorm, out + OFF_NN);
    k_scale_zavg<<<(V_CODES * D_DIM) / 256, 256, 0, stream>>>(zavg, out + OFF_ZAVG);
    k_split_w   <<<(V_CODES * D_DIM) / (256 * 8), 256, 0, stream>>>(w, Wh, Wl);
    k_split_x   <<<1024, 256, 0, stream>>>(x, Xh, Xl);

    dim3 grid(V_CODES / 128, M_ROWS / 128);
    k_mfma_argmin<<<grid, 256, 0, stream>>>(Xh, Xl, Wh, Wl, ws_wnorm, ws_best);

    k_scatter   <<<NELEM / 256, 256, 0, stream>>>(x, w, ws_best, out, ws_scal);
    k_finalize_n<<<1, 256, 0, stream>>>(out + OFF_NN, ws_scal, out + OFF_QDIFF);
    k_weight    <<<(V_CODES * D_DIM) / 256, 256, 0, stream>>>(out + OFF_ZAVG, out + OFF_NN, ws_scal, out + OFF_W);
}

// Round 3
// 962.030 us; speedup vs baseline: 2.9987x; 1.5428x over previous
//
#include <hip/hip_runtime.h>

// ---------------- problem constants ----------------
#define V_CODES 8192
#define D_DIM   256
#define SPATIAL 4096            // 16*16*16
#define M_ROWS  32768           // 8 * 4096
#define NELEM   8388608         // M_ROWS * D_DIM

static constexpr float GAMMA_F = 0.99f;
static constexpr float OMG_F   = (float)(1.0 - 0.99);
static constexpr float EPS_F   = 1e-7f;
static constexpr float VEPS_F  = (float)(8192 * 1e-7);

// output layout (floats), concatenated in reference return order
static constexpr size_t OFF_QUANT = 0;            // 8388608  quant_st
static constexpr size_t OFF_IDX   = 8388608;      // 32768    enc_idx (stored as float)
static constexpr size_t OFF_QDIFF = 8421376;      // 1        quant_diff
static constexpr size_t OFF_NN    = 8421377;      // 8192     new_N
static constexpr size_t OFF_ZAVG  = 8429569;      // 2097152  new_z_avg
static constexpr size_t OFF_W     = 10526721;     // 2097152  new_weight

typedef _Float16 f16x8 __attribute__((ext_vector_type(8)));
typedef float    f32x4 __attribute__((ext_vector_type(4)));

// async global->LDS, 16B per lane; LDS dest is wave-uniform base + lane*16
#define GLL(gp, lp) __builtin_amdgcn_global_load_lds( \
    (const __attribute__((address_space(1))) unsigned int*)(gp), \
    (__attribute__((address_space(3))) unsigned int*)(lp), 16, 0, 0)

// ---------------- K0a: weight row norms (fp32) ----------------
__global__ void k_wnorm(const float* __restrict__ W, float* __restrict__ wnorm) {
    int v = blockIdx.x * 4 + (threadIdx.x >> 6);
    int lane = threadIdx.x & 63;
    float4 w4 = *(const float4*)(W + (size_t)v * D_DIM + lane * 4);
    float s = w4.x * w4.x + w4.y * w4.y + w4.z * w4.z + w4.w * w4.w;
    #pragma unroll
    for (int m = 32; m > 0; m >>= 1) s += __shfl_xor(s, m, 64);
    if (lane == 0) wnorm[v] = s;
}

// ---------------- K0c: split W (V x 256, k-contiguous) into fp16 hi/lo planes ----------------
__global__ void k_split_w(const float* __restrict__ W, _Float16* __restrict__ Wh,
                          _Float16* __restrict__ Wl) {
    size_t i8 = ((size_t)blockIdx.x * 256 + threadIdx.x) * 8;
    float4 a = *(const float4*)(W + i8);
    float4 b = *(const float4*)(W + i8 + 4);
    float v[8] = {a.x, a.y, a.z, a.w, b.x, b.y, b.z, b.w};
    f16x8 hi, lo;
    #pragma unroll
    for (int j = 0; j < 8; j++) {
        _Float16 h = (_Float16)v[j];
        hi[j] = h;
        lo[j] = (_Float16)(v[j] - (float)h);
    }
    *(f16x8*)(Wh + i8) = hi;
    *(f16x8*)(Wl + i8) = lo;
}

// ---------------- K0d: split + transpose X (b,k,sp) -> Xh/Xl (m, k) row-major ----------------
__global__ void k_split_x(const float* __restrict__ X, _Float16* __restrict__ Xh,
                          _Float16* __restrict__ Xl) {
    int bid  = blockIdx.x;            // 1024 blocks
    int lane = threadIdx.x & 63;
    int kg   = (bid & 1) * 4 + (threadIdx.x >> 6);   // 0..7 -> k base kg*32
    int m    = (bid >> 1) * 64 + lane;
    int b  = m >> 12;
    int sp = m & 4095;
    const float* src = X + (size_t)b * (D_DIM * SPATIAL) + (size_t)(kg * 32) * SPATIAL + sp;
    float v[32];
    #pragma unroll
    for (int j = 0; j < 32; j++) v[j] = src[(size_t)j * SPATIAL];   // coalesced across lanes
    _Float16* dh = Xh + (size_t)m * D_DIM + kg * 32;
    _Float16* dl = Xl + (size_t)m * D_DIM + kg * 32;
    #pragma unroll
    for (int c = 0; c < 4; c++) {
        f16x8 hi, lo;
        #pragma unroll
        for (int j = 0; j < 8; j++) {
            float x = v[c * 8 + j];
            _Float16 h = (_Float16)x;
            hi[j] = h;
            lo[j] = (_Float16)(x - (float)h);
        }
        *(f16x8*)(dh + c * 8) = hi;
        *(f16x8*)(dl + c * 8) = lo;
    }
}

// ---------------- K1: MFMA distance GEMM + argmin (v-split, atomicMin merge) ----------------
__device__ inline unsigned long long packkey(float s, int v) {
    unsigned u = __float_as_uint(s);
    u = (u & 0x80000000u) ? ~u : (u | 0x80000000u);
    return ((unsigned long long)u << 32) | (unsigned)v;
}

__global__ __launch_bounds__(256, 2) void k_mfma_argmin(
        const _Float16* __restrict__ Xh, const _Float16* __restrict__ Xl,
        const _Float16* __restrict__ Wh, const _Float16* __restrict__ Wl,
        const float* __restrict__ wnorm, unsigned long long* __restrict__ best) {
    __shared__ __align__(16) _Float16 lds[16384];
    const int tid  = threadIdx.x;
    const int wid  = tid >> 6;
    const int lane = tid & 63;
    const int wy = wid >> 1, wx = wid & 1;
    const int lrow = lane & 15, lq = lane >> 4;
    const int m0 = blockIdx.y * 128;
    const int v0 = blockIdx.x * 128;

    f32x4 acc[4][4] = {};

    const _Float16* planes[4] = {Xh, Xl, Wh, Wl};
    const _Float16* P = planes[wid];
    const int rowb = (wid < 2 ? m0 : v0) + lrow;

    for (int k0 = 0; k0 < D_DIM; k0 += 32) {
        __syncthreads();
        #pragma unroll
        for (int sub = 0; sub < 8; sub++) {
            const _Float16* g = P + (size_t)(rowb + sub * 16) * D_DIM + k0 + lq * 8;
            GLL(g, &lds[(wid * 8 + sub) * 512]);
        }
        __syncthreads();
        f16x8 ah[4], al[4], bh[4], bl[4];
        #pragma unroll
        for (int i = 0; i < 4; i++) {
            ah[i] = *(const f16x8*)&lds[(      wy * 4 + i) * 512 + lane * 8];
            al[i] = *(const f16x8*)&lds[( 8 + wy * 4 + i) * 512 + lane * 8];
            bh[i] = *(const f16x8*)&lds[(16 + wx * 4 + i) * 512 + lane * 8];
            bl[i] = *(const f16x8*)&lds[(24 + wx * 4 + i) * 512 + lane * 8];
        }
        #pragma unroll
        for (int mi = 0; mi < 4; mi++)
            #pragma unroll
            for (int vi = 0; vi < 4; vi++) {
                acc[mi][vi] = __builtin_amdgcn_mfma_f32_16x16x32_f16(ah[mi], bh[vi], acc[mi][vi], 0, 0, 0);
                acc[mi][vi] = __builtin_amdgcn_mfma_f32_16x16x32_f16(al[mi], bh[vi], acc[mi][vi], 0, 0, 0);
                acc[mi][vi] = __builtin_amdgcn_mfma_f32_16x16x32_f16(ah[mi], bl[vi], acc[mi][vi], 0, 0, 0);
            }
    }

    float wnv[4];
    #pragma unroll
    for (int vi = 0; vi < 4; vi++) wnv[vi] = wnorm[v0 + (wx * 4 + vi) * 16 + lrow];

    #pragma unroll
    for (int mi = 0; mi < 4; mi++) {
        #pragma unroll
        for (int r = 0; r < 4; r++) {
            unsigned long long k = ~0ull;
            #pragma unroll
            for (int vi = 0; vi < 4; vi++) {
                int v = v0 + (wx * 4 + vi) * 16 + lrow;
                float s = wnv[vi] - 2.0f * acc[mi][vi][r];
                unsigned long long key = packkey(s, v);
                k = key < k ? key : k;
            }
            #pragma unroll
            for (int msk = 1; msk < 16; msk <<= 1) {
                unsigned long long o = __shfl_xor(k, msk, 64);
                k = o < k ? o : k;
            }
            if (lrow == 0) {
                int m = m0 + (wy * 4 + mi) * 16 + lq * 4 + r;
                atomicMin(&best[m], k);
            }
        }
    }
}

// ---------------- K2a: extract idx, count per code ----------------
__global__ void k_count(const unsigned long long* __restrict__ best,
                        int* __restrict__ counts, float* __restrict__ out) {
    int m = blockIdx.x * 256 + threadIdx.x;
    int v = (int)(unsigned)(best[m] & 0xFFFFFFFFull);
    atomicAdd(&counts[v], 1);
    out[OFF_IDX + m] = (float)v;
}

// ---------------- K2b: exclusive prefix over 8192 counts ----------------
__global__ void k_prefix(const int* __restrict__ counts, int* __restrict__ offsets,
                         int* __restrict__ cursor) {
    __shared__ int tsum[256];
    int t = threadIdx.x;
    int local[32];
    int s = 0;
    #pragma unroll
    for (int i = 0; i < 32; i++) { local[i] = s; s += counts[t * 32 + i]; }
    tsum[t] = s;
    __syncthreads();
    if (t == 0) {
        int run = 0;
        for (int i = 0; i < 256; i++) { int c = tsum[i]; tsum[i] = run; run += c; }
    }
    __syncthreads();
    int base = tsum[t];
    #pragma unroll
    for (int i = 0; i < 32; i++) {
        int o = base + local[i];
        offsets[t * 32 + i] = o;
        cursor[t * 32 + i]  = o;
    }
}

// ---------------- K2c: fill bins ----------------
__global__ void k_fill(const unsigned long long* __restrict__ best,
                       int* __restrict__ cursor, int* __restrict__ bin) {
    int m = blockIdx.x * 256 + threadIdx.x;
    int v = (int)(unsigned)(best[m] & 0xFFFFFFFFull);
    int pos = atomicAdd(&cursor[v], 1);
    bin[pos] = m;
}

// ---------------- K2d: per-code reduction -> new_N, new_z_avg (no atomics) ----------------
__global__ void k_codes(const _Float16* __restrict__ Xh, const _Float16* __restrict__ Xl,
                        const float* __restrict__ N, const float* __restrict__ zavg,
                        const int* __restrict__ counts, const int* __restrict__ offsets,
                        const int* __restrict__ bin, float* __restrict__ out) {
    int v = blockIdx.x;
    int d = threadIdx.x;
    int cnt = counts[v];
    int off = offsets[v];
    float s = 0.0f;
    for (int r = 0; r < cnt; r++) {
        int m = bin[off + r];
        s += (float)Xh[(size_t)m * D_DIM + d] + (float)Xl[(size_t)m * D_DIM + d];
    }
    out[OFF_ZAVG + (size_t)v * D_DIM + d] = GAMMA_F * zavg[(size_t)v * D_DIM + d] + OMG_F * s;
    if (d == 0) out[OFF_NN + v] = GAMMA_F * N[v] + OMG_F * (float)cnt;
}

// ---------------- K3: quant_st + quant_diff (float4 along sp) ----------------
__global__ void k_quant(const float* __restrict__ X, const float* __restrict__ W,
                        const unsigned long long* __restrict__ best, float* __restrict__ out,
                        float* __restrict__ ws_scal) {
    int e4 = blockIdx.x * 256 + threadIdx.x;    // element/4 in (b, d, sp) order
    int e  = e4 * 4;
    int sp = e & 4095;
    int bd = e >> 12;
    int d  = bd & 255;
    int b  = bd >> 8;
    int mb = b * SPATIAL + sp;
    float4 x4 = *(const float4*)(X + e);
    float q[4];
    float p = 0.0f;
    #pragma unroll
    for (int j = 0; j < 4; j++) {
        int v = (int)(unsigned)(best[mb + j] & 0xFFFFFFFFull);
        float wv = W[(size_t)v * D_DIM + d];
        float xv = (j == 0) ? x4.x : (j == 1) ? x4.y : (j == 2) ? x4.z : x4.w;
        q[j] = (wv - xv) + xv;                 // straight-through
        float df = xv - wv;
        p = fmaf(df, df, p);
    }
    *(float4*)(out + OFF_QUANT + e) = make_float4(q[0], q[1], q[2], q[3]);
    // block-reduce p -> one atomic
    #pragma unroll
    for (int msk = 32; msk > 0; msk >>= 1) p += __shfl_xor(p, msk, 64);
    __shared__ float red[4];
    int lane = threadIdx.x & 63, w = threadIdx.x >> 6;
    if (lane == 0) red[w] = p;
    __syncthreads();
    if (threadIdx.x == 0)
        atomicAdd(ws_scal, red[0] + red[1] + red[2] + red[3]);
}

// ---------------- K4a: n = sum(new_N); finalize quant_diff ----------------
__global__ void k_finalize_n(const float* __restrict__ outNN, float* __restrict__ ws_scal,
                             float* __restrict__ out_qdiff) {
    __shared__ float red[256];
    float s = 0.0f;
    for (int v = threadIdx.x; v < V_CODES; v += 256) s += outNN[v];
    red[threadIdx.x] = s;
    __syncthreads();
    #pragma unroll
    for (int t = 128; t > 0; t >>= 1) {
        if (threadIdx.x < t) red[threadIdx.x] += red[threadIdx.x + t];
        __syncthreads();
    }
    if (threadIdx.x == 0) {
        ws_scal[1] = red[0];
        out_qdiff[0] = ws_scal[0] * (1.0f / 8388608.0f);
    }
}

// ---------------- K4b: new_weight = new_z_avg / w ----------------
__global__ void k_weight(const float* __restrict__ zavg_out, const float* __restrict__ nn_out,
                         const float* __restrict__ ws_scal, float* __restrict__ out_w) {
    int i = blockIdx.x * 256 + threadIdx.x;
    int v = i >> 8;
    float n = ws_scal[1];
    float w = (nn_out[v] + EPS_F) / (n + VEPS_F) * n;
    out_w[i] = zavg_out[i] / w;
}

extern "C" void kernel_launch(void* const* d_in, const int* in_sizes, int n_in,
                              void* d_out, int out_size, void* d_ws, size_t ws_size,
                              hipStream_t stream) {
    const float* x    = (const float*)d_in[0];
    const float* w    = (const float*)d_in[1];
    const float* N    = (const float*)d_in[2];
    const float* zavg = (const float*)d_in[3];
    float* out = (float*)d_out;
    char*  wsb = (char*)d_ws;

    // workspace layout (bytes)
    float* ws_scal   = (float*)wsb;                      // 64 B   [0]=qdiff sum [1]=n
    int*   ws_counts = (int*)(wsb + 64);                 // 32 KB
    float* ws_wnorm  = (float*)(wsb + 32832);            // 32 KB
    int*   ws_off    = (int*)(wsb + 65600);              // 32 KB
    int*   ws_cur    = (int*)(wsb + 98368);              // 32 KB
    int*   ws_bin    = (int*)(wsb + 131136);             // 128 KB
    unsigned long long* ws_best = (unsigned long long*)(wsb + 262208);  // 256 KB
    _Float16* Xh = (_Float16*)(wsb + 524352);            // 16.78 MB
    _Float16* Xl = (_Float16*)(wsb + 524352 + 16777216);
    _Float16* Wh = (_Float16*)(wsb + 524352 + 2 * 16777216);  // 4.19 MB
    _Float16* Wl = (_Float16*)(wsb + 524352 + 2 * 16777216 + 4194304);
    // total ~42.5 MB

    hipMemsetAsync(wsb, 0, 32832, stream);                       // scal + counts
    hipMemsetAsync(ws_best, 0xFF, (size_t)M_ROWS * 8, stream);

    k_wnorm  <<<V_CODES / 4, 256, 0, stream>>>(w, ws_wnorm);
    k_split_w<<<(V_CODES * D_DIM) / (256 * 8), 256, 0, stream>>>(w, Wh, Wl);
    k_split_x<<<1024, 256, 0, stream>>>(x, Xh, Xl);

    dim3 grid(V_CODES / 128, M_ROWS / 128);
    k_mfma_argmin<<<grid, 256, 0, stream>>>(Xh, Xl, Wh, Wl, ws_wnorm, ws_best);

    k_count  <<<M_ROWS / 256, 256, 0, stream>>>(ws_best, ws_counts, out);
    k_prefix <<<1, 256, 0, stream>>>(ws_counts, ws_off, ws_cur);
    k_fill   <<<M_ROWS / 256, 256, 0, stream>>>(ws_best, ws_cur, ws_bin);
    k_codes  <<<V_CODES, 256, 0, stream>>>(Xh, Xl, N, zavg, ws_counts, ws_off, ws_bin, out);
    k_quant  <<<NELEM / (256 * 4), 256, 0, stream>>>(x, w, ws_best, out, ws_scal);

    k_finalize_n<<<1, 256, 0, stream>>>(out + OFF_NN, ws_scal, out + OFF_QDIFF);
    k_weight <<<(V_CODES * D_DIM) / 256, 256, 0, stream>>>(out + OFF_ZAVG, out + OFF_NN, ws_scal, out + OFF_W);
}